// Round 4
// baseline (395.225 us; speedup 1.0000x reference)
//
#include <hip/hip_runtime.h>
#include <stdint.h>

#define NROWS 16384
#define KDIM  512
#define BM 256
#define BN 256
#define CT 2
#define NCHUNK 32           // 16384 / (BN*CT)
#define NPHASE 16           // K-halves of 32 elems: 512/32
#define INV_T 14.285714285714286f
#define LOG2E 1.4426950408889634f
#define LN2   0.6931471805599453f

typedef __bf16 bf16x8 __attribute__((ext_vector_type(8)));
typedef float  f32x16 __attribute__((ext_vector_type(16)));
typedef unsigned short u16x8 __attribute__((ext_vector_type(8)));

// async global->LDS, 16B/lane; LDS dest = wave-uniform base + lane*16
__device__ __forceinline__ void gload_lds16(const void* gptr, void* lptr) {
    uint32_t loff = (uint32_t)(uintptr_t)lptr;
    loff = __builtin_amdgcn_readfirstlane(loff);
    __builtin_amdgcn_global_load_lds(
        (const uint32_t __attribute__((address_space(1)))*)(uintptr_t)gptr,
        (uint32_t __attribute__((address_space(3)))*)(uintptr_t)loff,
        16, 0, 0);
}

// Fragment-major panel layout for mfma_32x32x16_bf16:
//   granule(row r, K-half kh, q=elem-octet 0..3) lives at index
//   ((kh*512 + (r>>5))*2 + (q>>1))*64 + ((q&1)<<5) + (r&31)   (16B granules)
// so that MFMA lane l of (R-group, ks) reads granule base + l — lane-contiguous.

// ---- kernel 1: L2 normalize + scale + bf16 cast into fragment-major panel ----
__global__ void k_norm(const float* __restrict__ X, char* __restrict__ Y, float scale) {
    const int row  = blockIdx.x * 4 + (threadIdx.x >> 6);
    const int lane = threadIdx.x & 63;
    const float* xr = X + (size_t)row * KDIM + lane * 8;
    float4 a = *(const float4*)xr;
    float4 b = *(const float4*)(xr + 4);
    float ss = a.x*a.x + a.y*a.y + a.z*a.z + a.w*a.w
             + b.x*b.x + b.y*b.y + b.z*b.z + b.w*b.w;
    #pragma unroll
    for (int off = 1; off < 64; off <<= 1) ss += __shfl_xor(ss, off);
    const float s = scale / fmaxf(sqrtf(ss), 1e-12f);
    __bf16 o[8];
    o[0] = (__bf16)(a.x * s); o[1] = (__bf16)(a.y * s);
    o[2] = (__bf16)(a.z * s); o[3] = (__bf16)(a.w * s);
    o[4] = (__bf16)(b.x * s); o[5] = (__bf16)(b.y * s);
    o[6] = (__bf16)(b.z * s); o[7] = (__bf16)(b.w * s);
    const int kh = lane >> 2, q = lane & 3;
    const size_t gr = ((size_t)(kh * 512 + (row >> 5)) * 2 + (q >> 1)) * 64
                    + ((q & 1) << 5) + (row & 31);
    *(u16x8*)(Y + gr * 16) = *(const u16x8*)o;
}

// ---- kernel 2: fused GEMM + exp2 + row-sum. 256x256, BK-half=32, 8 waves (2x4),
// 32x32x16 MFMA, 4-slot LDS ring, counted vmcnt (4 loads stay in flight).
__global__ __launch_bounds__(512, 1) void k_gemm(const char* __restrict__ A,
                                                 const char* __restrict__ B,
                                                 float* __restrict__ S_part) {
    __shared__ __align__(16) char L[4 * 32768];   // 4 slots x (A-half 16KB + B-half 16KB)
    __shared__ float rowsum[4][BM];

    const int tid  = threadIdx.x;
    const int lane = tid & 63;
    const int w    = tid >> 6;           // 0..7
    const int wr   = w >> 2, wc = w & 3; // 2 x 4 wave grid
    // XCD supertile swizzle: xcd = bid&7; per XCD 8 supertiles of (8 brow x 4 chunk)
    const int bid  = blockIdx.x;
    const int xcd  = bid & 7;
    const int idx  = bid >> 3;           // 0..255
    const int st   = idx >> 5;           // supertile 0..7
    const int wsub = idx & 31;
    const int brow  = (st * 8 + (wsub >> 2)) * BM;
    const int chunk = xcd * 4 + (wsub & 3);   // 0..31

    // per-thread ds_read base: lane-contiguous fragments
    const int lbyte = lane * 16;

#define STAGE(h_, s_) do {                                               \
        const char* ga_ = A + (size_t)((h_) * NROWS + brow) * 64 + tid * 16; \
        const char* gb_ = B + (size_t)((h_) * NROWS + bcol) * 64 + tid * 16; \
        char* la_ = L + (s_) * 32768 + tid * 16;                         \
        gload_lds16(ga_,        la_);                                    \
        gload_lds16(ga_ + 8192, la_ + 8192);                             \
        gload_lds16(gb_,        la_ + 16384);                            \
        gload_lds16(gb_ + 8192, la_ + 24576);                            \
    } while (0)

    float rowacc = 0.f;
    for (int ct = 0; ct < CT; ++ct) {
        const int bcol = (chunk * CT + ct) * BN;
        f32x16 acc[4][2] = {};   // 4 m-tiles x 2 n-tiles of 32x32

        STAGE(0, 0);
        STAGE(1, 1);
        asm volatile("s_waitcnt vmcnt(4)" ::: "memory");
        __builtin_amdgcn_s_barrier();
        __builtin_amdgcn_sched_barrier(0);

        #pragma unroll
        for (int h = 0; h < NPHASE; ++h) {
            if (h < NPHASE - 2) STAGE(h + 2, (h + 2) & 3);
            const char* sl = L + (h & 3) * 32768;
            // A frags: m-tile R-group = wr*4+m, k-step ks: offset ((wr*4+m)*2+ks)*1024
            // B frags: R-group wc*2+n: 16384 + ((wc*2+n)*2+ks)*1024
            bf16x8 af[4][2], bf[2][2];
            #pragma unroll
            for (int m = 0; m < 4; ++m)
                #pragma unroll
                for (int ks = 0; ks < 2; ++ks)
                    af[m][ks] = *(const bf16x8*)(sl + ((wr * 4 + m) * 2 + ks) * 1024 + lbyte);
            #pragma unroll
            for (int n = 0; n < 2; ++n)
                #pragma unroll
                for (int ks = 0; ks < 2; ++ks)
                    bf[n][ks] = *(const bf16x8*)(sl + 16384 + ((wc * 2 + n) * 2 + ks) * 1024 + lbyte);
            __builtin_amdgcn_s_setprio(1);
            #pragma unroll
            for (int m = 0; m < 4; ++m)
                #pragma unroll
                for (int n = 0; n < 2; ++n)
                    #pragma unroll
                    for (int ks = 0; ks < 2; ++ks)
                        acc[m][n] = __builtin_amdgcn_mfma_f32_32x32x16_bf16(
                            af[m][ks], bf[n][ks], acc[m][n], 0, 0, 0);
            __builtin_amdgcn_s_setprio(0);
            if (h < NPHASE - 2)       asm volatile("s_waitcnt vmcnt(4)" ::: "memory");
            else if (h == NPHASE - 2) asm volatile("s_waitcnt vmcnt(0)" ::: "memory");
            __builtin_amdgcn_s_barrier();
            __builtin_amdgcn_sched_barrier(0);
        }

        // epilogue: C/D 32x32 layout: col = lane&31, row = (reg&3)+8*(reg>>2)+4*(lane>>5)
        #pragma unroll
        for (int m = 0; m < 4; ++m) {
            float rs[16];
            #pragma unroll
            for (int r = 0; r < 16; ++r)
                rs[r] = __builtin_amdgcn_exp2f(acc[m][0][r])
                      + __builtin_amdgcn_exp2f(acc[m][1][r]);
            #pragma unroll
            for (int off = 16; off >= 1; off >>= 1)
                #pragma unroll
                for (int r = 0; r < 16; ++r)
                    rs[r] += __shfl_xor(rs[r], off);
            if ((lane & 31) == 0) {
                const int rb = wr * 128 + m * 32 + (lane >> 5) * 4;
                #pragma unroll
                for (int r = 0; r < 16; ++r)
                    rowsum[wc][rb + (r & 3) + 8 * (r >> 2)] = rs[r];
            }
        }
        __syncthreads();
        if (tid < BM)
            rowacc += rowsum[0][tid] + rowsum[1][tid] + rowsum[2][tid] + rowsum[3][tid];
        __syncthreads();
    }
#undef STAGE
    if (tid < BM) S_part[(size_t)chunk * NROWS + brow + tid] = rowacc;
}

// ---- kernel 3: diagonal logits (log2-scaled), fragment-major panel ----
__global__ void k_diag(const char* __restrict__ A, const char* __restrict__ B,
                       float* __restrict__ diag) {
    const int row  = blockIdx.x * 4 + (threadIdx.x >> 6);
    const int lane = threadIdx.x & 63;
    const int kh = lane >> 2, q = lane & 3;
    const size_t gr = ((size_t)(kh * 512 + (row >> 5)) * 2 + (q >> 1)) * 64
                    + ((q & 1) << 5) + (row & 31);
    const bf16x8 va = *(const bf16x8*)(A + gr * 16);
    const bf16x8 vb = *(const bf16x8*)(B + gr * 16);
    float d = 0.f;
    #pragma unroll
    for (int i = 0; i < 8; ++i) d += (float)va[i] * (float)vb[i];
    #pragma unroll
    for (int off2 = 1; off2 < 64; off2 <<= 1) d += __shfl_xor(d, off2);
    if (lane == 0) diag[row] = d;
}

// ---- kernel 4: per-row loss + deterministic block partials ----
__global__ void k_loss(const float* __restrict__ S_part, const float* __restrict__ diag,
                       float* __restrict__ partial) {
    const int g = blockIdx.x * 256 + threadIdx.x;
    float S = 0.f;
    #pragma unroll
    for (int c = 0; c < NCHUNK; ++c) S += S_part[(size_t)c * NROWS + g];
    float v = logf(S) - diag[g] * LN2;   // diag is log2-scaled
    __shared__ float wsum[4];
    #pragma unroll
    for (int off = 1; off < 64; off <<= 1) v += __shfl_xor(v, off);
    if ((threadIdx.x & 63) == 0) wsum[threadIdx.x >> 6] = v;
    __syncthreads();
    if (threadIdx.x == 0) partial[blockIdx.x] = wsum[0] + wsum[1] + wsum[2] + wsum[3];
}

__global__ void k_final(const float* __restrict__ partial, float* __restrict__ out) {
    float v = partial[threadIdx.x];
    #pragma unroll
    for (int off = 1; off < 64; off <<= 1) v += __shfl_xor(v, off);
    if (threadIdx.x == 0) out[0] = v * (1.0f / (float)NROWS);
}

extern "C" void kernel_launch(void* const* d_in, const int* in_sizes, int n_in,
                              void* d_out, int out_size, void* d_ws, size_t ws_size,
                              hipStream_t stream) {
    const float* f1 = (const float*)d_in[0];
    const float* f2 = (const float*)d_in[1];
    float* out = (float*)d_out;

    char* ws = (char*)d_ws;
    char*  f1p   = ws;                                  // 16 MB panel
    char*  f2p   = ws + (16u << 20);                    // 16 MB panel
    float* S_part = (float*)(ws + (32u << 20));         // 2 MB [NCHUNK][NROWS]
    float* diag   = (float*)(ws + (34u << 20));         // 64 KB
    float* part   = (float*)(ws + (34u << 20) + (1u << 16)); // 256 B

    k_norm<<<dim3(NROWS / 4), dim3(256), 0, stream>>>(f1, f1p, INV_T * LOG2E);
    k_norm<<<dim3(NROWS / 4), dim3(256), 0, stream>>>(f2, f2p, 1.0f);
    k_gemm<<<dim3((NROWS / BM) * NCHUNK), dim3(512), 0, stream>>>(f1p, f2p, S_part);
    k_diag<<<dim3(NROWS / 4), dim3(256), 0, stream>>>(f1p, f2p, diag);
    k_loss<<<dim3(NROWS / 256), dim3(256), 0, stream>>>(S_part, diag, part);
    k_final<<<dim3(1), dim3(64), 0, stream>>>(part, out);
}